// Round 15
// baseline (92.439 us; speedup 1.0000x reference)
//
#include <hip/hip_runtime.h>
#include <stdint.h>

// ---------------------------------------------------------------------------
// OutputLayerReverseSegments, round 15: r14 base + W staged in LDS per block.
// out[b,f,c] = sum_i x[b,c,t_i(f),:] . W_i[p_i(f),:] + sum_i b_i[p_i(f)]
// B=64, C=64, T=63, D=256, F=720, partitions k = {1,2,4,8,16,32}
//
// r14's L1-based W sharing was neutral (wave drift defeats it); r13/r6/r7
// showed W-request volume moves perf +-12-15%. This round makes the sharing
// explicit: tok7-62 block = (one token, 4 consecutive ntiles); the block
// cooperatively copies its chunk's W subtiles (<=3 x 8KB, CH=3) into LDS
// ONCE, one __syncthreads (before any atomics -> free drain), then all 4
// waves MFMA from LDS with no further barriers. W L2 traffic 306 -> ~40 MB.
// tok0-6 keep the r14 LDS-shared-x roles verbatim (no W overlap there).
// c32 waves, unsafeAtomicAdd, setprio, fused prepinit (out = bias(f)).
// Blocks: 768 shx + 512 (tok7-14, 2 chunks) + 512 (tok15-30) + 1024
// (tok31-62) = 2816.
// ---------------------------------------------------------------------------

#define FDIM 720
#define DDIM 256
#define TDIM 63
#define NSUBTOT 299                              // sum over (i,j) of ceil(len/16)
#define TAB_BYTES ((size_t)NSUBTOT * 8 * 1024)   // 2,449,408
#define OUTELEMS ((size_t)64 * FDIM * 64)        // 2,949,120
#define NPREPTHR (NSUBTOT * 8 * 64)              // 153,088

typedef __attribute__((ext_vector_type(8))) short short8;
typedef __attribute__((ext_vector_type(4))) float f32x4;

// pack 2 f32 -> 2 bf16 (round-half-up) in one u32: 2 adds + 1 v_perm
__device__ __forceinline__ uint32_t pkru(float a, float b) {
    uint32_t ua = __builtin_bit_cast(uint32_t, a) + 0x8000u;
    uint32_t ub = __builtin_bit_cast(uint32_t, b) + 0x8000u;
    return __builtin_amdgcn_perm(ub, ua, 0x07060302u);
}
__device__ __forceinline__ short8 loadpack(const float* p) {
    float4 v0 = *(const float4*)p;
    float4 v1 = *(const float4*)(p + 4);
    uint4 u;
    u.x = pkru(v0.x, v0.y);
    u.y = pkru(v0.z, v0.w);
    u.z = pkru(v1.x, v1.y);
    u.w = pkru(v1.z, v1.w);
    return __builtin_bit_cast(short8, u);
}

// HW float atomic add (avoid CAS-loop lowering)
__device__ __forceinline__ void atomAddF(float* p, float v) {
    unsafeAtomicAdd(p, v);
}

// partition index / position within part, for partition i at forecast f
__device__ __forceinline__ void jpos(int i, int f, int& j, int& pos) {
    switch (i) {
        case 0: j = 0;       pos = f;            break;
        case 1: j = f / 360; pos = f - 360 * j;  break;
        case 2: j = f / 180; pos = f - 180 * j;  break;
        case 3: j = f / 90;  pos = f - 90 * j;   break;
        case 4: j = f / 45;  pos = f - 45 * j;   break;
        default:
            if (f < 368) { j = f / 23;  pos = f - 23 * j; }
            else { int g = f - 368; int q = g / 22; j = 16 + q; pos = g - 22 * q; }
            break;
    }
}

// per-token parameters
__device__ __forceinline__ void tok_params(int tok, int& len, int& ns,
                                           int& start, int& tabsub) {
    if (tok < 1)       { len = 720; ns = 45; start = 0;
                         tabsub = 0; }
    else if (tok < 3)  { int j = tok - 1;  len = 360; ns = 23; start = 360 * j;
                         tabsub = 45 + j * 23; }
    else if (tok < 7)  { int j = tok - 3;  len = 180; ns = 12; start = 180 * j;
                         tabsub = 91 + j * 12; }
    else if (tok < 15) { int j = tok - 7;  len = 90;  ns = 6;  start = 90 * j;
                         tabsub = 139 + j * 6; }
    else if (tok < 31) { int j = tok - 15; len = 45;  ns = 3;  start = 45 * j;
                         tabsub = 187 + j * 3; }
    else               { int j = tok - 31;
                         len = (j < 16) ? 23 : 22;
                         start = (j < 16) ? 23 * j : 368 + 22 * (j - 16);
                         ns = 2; tabsub = 235 + j * 2; }
}

// ---------------------------------------------------------------------------
// Fused prep + init (unchanged from r11/r14).
// ---------------------------------------------------------------------------
__global__ __launch_bounds__(256) void olrs_prepinit(
    const float* __restrict__ W0, const float* __restrict__ W1,
    const float* __restrict__ W2, const float* __restrict__ W3,
    const float* __restrict__ W4, const float* __restrict__ W5,
    const float* __restrict__ b0, const float* __restrict__ b1,
    const float* __restrict__ b2, const float* __restrict__ b3,
    const float* __restrict__ b4, const float* __restrict__ b5,
    char* __restrict__ ws, float* __restrict__ out)
{
    const int gid = blockIdx.x * 256 + threadIdx.x;

    const size_t base = (size_t)gid * 4;
    if (base < OUTELEMS) {
        const int f = (int)((base >> 6) % FDIM);
        int j, p;
        float s = b0[f];
        jpos(1, f, j, p); s += b1[p];
        jpos(2, f, j, p); s += b2[p];
        jpos(3, f, j, p); s += b3[p];
        jpos(4, f, j, p); s += b4[p];
        jpos(5, f, j, p); s += b5[p];
        float4 o = {s, s, s, s};
        *(float4*)(out + base) = o;
    }

    if (gid < NPREPTHR) {
        const int lane = gid & 63;
        const int fid  = gid >> 6;
        const int ks = fid & 7;
        const int g  = fid >> 3;      // global subtile 0..298

        int len; const float* W; int s;
        if (g < 45)       { W = W0; len = 720; s = g; }
        else if (g < 91)  { int g2 = g - 45;  W = W1; len = 360; s = g2 % 23; }
        else if (g < 139) { int g2 = g - 91;  W = W2; len = 180; s = g2 % 12; }
        else if (g < 187) { int g2 = g - 139; W = W3; len = 90;  s = g2 % 6; }
        else if (g < 235) { int g2 = g - 187; W = W4; len = 45;  s = g2 % 3; }
        else              { int g2 = g - 235; W = W5; int j = g2 >> 1;
                            len = (j < 16) ? 23 : 22; s = g2 & 1; }

        const int m15  = lane & 15;
        const int koct = lane >> 4;
        const int pos  = s * 16 + m15;
        uint4 u = {0u, 0u, 0u, 0u};
        if (pos < len) {
            const float* src = W + (size_t)pos * DDIM + ks * 32 + koct * 8;
            float4 v0 = *(const float4*)src;
            float4 v1 = *(const float4*)(src + 4);
            u.x = pkru(v0.x, v0.y);
            u.y = pkru(v0.z, v0.w);
            u.z = pkru(v1.x, v1.y);
            u.w = pkru(v1.z, v1.w);
        }
        *(uint4*)(ws + (size_t)fid * 1024 + lane * 16) = u;
    }
}

// ---------------------------------------------------------------------------
// Main:
//  blocks [0,768)    : rid 0..5, tok0-6 LDS-shared-x roles (r14 verbatim).
//  blocks [768,2816) : W-shared path -- block = (token, chunk<=3, 4 ntiles);
//                      W chunk staged to LDS once, 1 barrier, then
//                      barrier-free compute from LDS.
// ---------------------------------------------------------------------------
__global__ __launch_bounds__(256) void olrs_main15(
    const float* __restrict__ x,
    const char* __restrict__ ws,
    float* __restrict__ out)
{
    __shared__ char lds[32768];

    const int bid   = blockIdx.x;
    const int w     = threadIdx.x >> 6;
    const int lane  = threadIdx.x & 63;
    const int m15   = lane & 15;
    const int koct  = lane >> 4;

    if (bid < 768) {
        // ============== tok0-6: LDS-shared x slabs (r14 verbatim) ==========
        const int rid   = bid >> 7;      // 0..5
        const int ntile = bid & 127;
        const int b     = ntile >> 1;
        const int c0    = (ntile & 1) << 5;

        int tok, s0, slab;
        if (rid < 2)      { tok = 0;             s0 = rid * 24 + w * 6; slab = 0; }
        else if (rid < 4) { tok = rid - 1;       s0 = w * 6;            slab = 0; }
        else              { int tb = 3 + (rid - 4) * 2;
                            tok = tb + (w >> 1); s0 = (w & 1) * 6;      slab = w >> 1; }

        int len, ns, start, tabsub;
        tok_params(tok, len, ns, start, tabsub);
        const int send = (s0 + 6 < ns) ? (s0 + 6) : ns;

        const int nslab   = (rid >= 4) ? 2 : 1;
        const int tokbase = (rid < 2) ? 0 : ((rid < 4) ? (rid - 1) : 3 + (rid - 4) * 2);
        const int cc = threadIdx.x >> 3;   // 0..31
        const int t8 = threadIdx.x & 7;    // 0..7
        for (int sl = 0; sl < nslab; sl++) {
            const float* src = x + (((size_t)(b * 64 + c0 + cc)) * TDIM + tokbase + sl) * DDIM;
            char* dst = lds + sl * 16384;
            #pragma unroll
            for (int rep = 0; rep < 4; rep++) {
                const int d8 = t8 + rep * 8;            // 0..31
                float4 v0 = *(const float4*)(src + d8 * 8);
                float4 v1 = *(const float4*)(src + d8 * 8 + 4);
                uint4 u;
                u.x = pkru(v0.x, v0.y);
                u.y = pkru(v0.z, v0.w);
                u.z = pkru(v1.x, v1.y);
                u.w = pkru(v1.z, v1.w);
                const int slot = ((d8 >> 2) * 2 + (cc >> 4)) * 64
                               + (d8 & 3) * 16 + (cc & 15);
                *(uint4*)(dst + slot * 16) = u;
            }
        }
        __syncthreads();
        short8 xl[8], xh[8];
        const char* sb = lds + slab * 16384;
        #pragma unroll
        for (int ks = 0; ks < 8; ks++) {
            xl[ks] = *(const short8*)(sb + ((ks * 2 + 0) * 64 + lane) * 16);
            xh[ks] = *(const short8*)(sb + ((ks * 2 + 1) * 64 + lane) * 16);
        }

        const char* tab = ws + (size_t)tabsub * 8192 + lane * 16;
        float* obl = out + ((size_t)b * FDIM + start) * 64 + c0 + m15;
        float* obh = obl + 16;

        short8 wA[8], wB[8];
        auto loadW = [&](short8* wreg, int s) {
            const char* t = tab + (size_t)s * 8192;
            #pragma unroll
            for (int ks = 0; ks < 8; ks++)
                wreg[ks] = *(const short8*)(t + ks * 1024);
        };
        auto compute = [&](const short8* wreg, int s) {
            f32x4 al0 = {0.f, 0.f, 0.f, 0.f}, al1 = {0.f, 0.f, 0.f, 0.f};
            f32x4 ah0 = {0.f, 0.f, 0.f, 0.f}, ah1 = {0.f, 0.f, 0.f, 0.f};
            __builtin_amdgcn_s_setprio(1);
            #pragma unroll
            for (int ks = 0; ks < 8; ks += 2) {
                al0 = __builtin_amdgcn_mfma_f32_16x16x32_bf16(wreg[ks],     xl[ks],     al0, 0, 0, 0);
                ah0 = __builtin_amdgcn_mfma_f32_16x16x32_bf16(wreg[ks],     xh[ks],     ah0, 0, 0, 0);
                al1 = __builtin_amdgcn_mfma_f32_16x16x32_bf16(wreg[ks + 1], xl[ks + 1], al1, 0, 0, 0);
                ah1 = __builtin_amdgcn_mfma_f32_16x16x32_bf16(wreg[ks + 1], xh[ks + 1], ah1, 0, 0, 0);
            }
            __builtin_amdgcn_s_setprio(0);
            const int fl0 = s * 16 + koct * 4;
            #pragma unroll
            for (int rg = 0; rg < 4; rg++) {
                const int fl = fl0 + rg;
                if (fl < len) {
                    atomAddF(obl + (size_t)fl * 64, al0[rg] + al1[rg]);
                    atomAddF(obh + (size_t)fl * 64, ah0[rg] + ah1[rg]);
                }
            }
        };

        int s = s0;
        loadW(wA, s);
        for (;;) {
            if (s + 1 < send) loadW(wB, s + 1);
            compute(wA, s);
            if (++s >= send) break;
            if (s + 1 < send) loadW(wA, s + 1);
            compute(wB, s);
            if (++s >= send) break;
        }
    } else {
        // ============== tok7-62: W staged in LDS, shared by 4 waves ========
        const int idx = bid - 768;
        int tok, s0g, g;
        if (idx < 512)       { int q = idx >> 5; g = idx & 31;
                               tok = 7 + (q >> 1); s0g = (q & 1) * 3; }
        else if (idx < 1024) { int q = idx - 512; g = q & 31;
                               tok = 15 + (q >> 5); s0g = 0; }
        else                 { int q = idx - 1024; g = q & 31;
                               tok = 31 + (q >> 5); s0g = 0; }

        int len, ns, start, tabsub;
        tok_params(tok, len, ns, start, tabsub);
        const int send = (s0g + 3 < ns) ? (s0g + 3) : ns;
        const int nsub = send - s0g;               // 2 or 3

        const int ntile = g * 4 + w;
        const int b     = ntile >> 1;
        const int c0    = (ntile & 1) << 5;

        // ---- stage W chunk into LDS (nsub * 8 KB), cooperative, coalesced
        {
            const char* src = ws + (size_t)(tabsub + s0g) * 8192;
            const int nrep = nsub * 2;             // 4 KB per rep
            for (int r = 0; r < nrep; r++) {
                const int off = threadIdx.x * 16 + r * 4096;
                *(uint4*)(lds + off) = *(const uint4*)(src + off);
            }
        }

        // ---- x slab: per-wave register load (issues overlap staging)
        const float* xpl = x + (((size_t)(b * 64 + c0 + m15)) * TDIM + tok) * DDIM;
        const float* xph = xpl + (size_t)16 * TDIM * DDIM;
        short8 xl[8], xh[8];
        #pragma unroll
        for (int ks = 0; ks < 8; ks++)
            xl[ks] = loadpack(xpl + ks * 32 + koct * 8);
        #pragma unroll
        for (int ks = 0; ks < 8; ks++)
            xh[ks] = loadpack(xph + ks * 32 + koct * 8);

        __syncthreads();   // W staged; no atomics outstanding -> cheap drain

        float* obl = out + ((size_t)b * FDIM + start) * 64 + c0 + m15;
        float* obh = obl + 16;

        for (int s = s0g; s < send; s++) {
            const char* tsub = lds + (size_t)(s - s0g) * 8192 + lane * 16;
            f32x4 al0 = {0.f, 0.f, 0.f, 0.f}, al1 = {0.f, 0.f, 0.f, 0.f};
            f32x4 ah0 = {0.f, 0.f, 0.f, 0.f}, ah1 = {0.f, 0.f, 0.f, 0.f};
            __builtin_amdgcn_s_setprio(1);
            #pragma unroll
            for (int ks = 0; ks < 8; ks += 2) {
                short8 w0 = *(const short8*)(tsub + ks * 1024);
                short8 w1 = *(const short8*)(tsub + (ks + 1) * 1024);
                al0 = __builtin_amdgcn_mfma_f32_16x16x32_bf16(w0, xl[ks],     al0, 0, 0, 0);
                ah0 = __builtin_amdgcn_mfma_f32_16x16x32_bf16(w0, xh[ks],     ah0, 0, 0, 0);
                al1 = __builtin_amdgcn_mfma_f32_16x16x32_bf16(w1, xl[ks + 1], al1, 0, 0, 0);
                ah1 = __builtin_amdgcn_mfma_f32_16x16x32_bf16(w1, xh[ks + 1], ah1, 0, 0, 0);
            }
            __builtin_amdgcn_s_setprio(0);
            const int fl0 = s * 16 + koct * 4;
            #pragma unroll
            for (int rg = 0; rg < 4; rg++) {
                const int fl = fl0 + rg;
                if (fl < len) {
                    atomAddF(obl + (size_t)fl * 64, al0[rg] + al1[rg]);
                    atomAddF(obh + (size_t)fl * 64, ah0[rg] + ah1[rg]);
                }
            }
        }
    }
}

// ---------------------------------------------------------------------------
// Fallback (tiny ws): wave-independent direct-load kernel (round 3).
// ---------------------------------------------------------------------------
__device__ __forceinline__ int startf(int i, int j) {
    switch (i) {
        case 0: return 0;
        case 1: return 360 * j;
        case 2: return 180 * j;
        case 3: return 90 * j;
        case 4: return 45 * j;
        default: return (j < 16) ? 23 * j : 368 + 22 * (j - 16);
    }
}

__global__ __launch_bounds__(256) void olrs_fb(
    const float* __restrict__ x,
    const float* __restrict__ W0, const float* __restrict__ b0,
    const float* __restrict__ W1, const float* __restrict__ b1,
    const float* __restrict__ W2, const float* __restrict__ b2,
    const float* __restrict__ W3, const float* __restrict__ b3,
    const float* __restrict__ W4, const float* __restrict__ b4,
    const float* __restrict__ W5, const float* __restrict__ b5,
    float* __restrict__ out)
{
    const float* Wp[6] = {W0, W1, W2, W3, W4, W5};
    const float* bp[6] = {b0, b1, b2, b3, b4, b5};
    const int TB[6] = {0, 1, 3, 7, 15, 31};

    const int wid  = blockIdx.x * 4 + (threadIdx.x >> 6);
    const int lane = threadIdx.x & 63;
    const int ft   = wid % 45;
    const int bc   = wid / 45;
    const int b    = bc >> 2;
    const int c0   = (bc & 3) << 4;
    const int f0   = ft << 4;
    const int m15  = lane & 15;
    const int koct = lane >> 4;
    const size_t xrow = (size_t)(b * 64 + c0 + m15) * TDIM;

    f32x4 acc = {0.f, 0.f, 0.f, 0.f};
    #pragma unroll
    for (int i = 0; i < 6; i++) {
        int jlo, plo, jhi, phi;
        jpos(i, f0, jlo, plo);
        jpos(i, f0 + 15, jhi, phi);
        const bool cross = (jhi > jlo);
        const int fb = cross ? (startf(i, jhi) - f0) : 16;
        const float* xlo = x + (xrow + TB[i] + jlo) * DDIM;
        const float* xhi = x + (xrow + TB[i] + jhi) * DDIM;
        int jw, pw;
        jpos(i, f0 + m15, jw, pw);
        const float* wsrc = Wp[i] + (size_t)pw * DDIM;
        #pragma unroll
        for (int ks = 0; ks < 8; ks++) {
            const int d0 = ks * 32 + koct * 8;
            short8 a = loadpack(wsrc + d0);
            short8 blo = loadpack(xlo + d0);
            if (!cross) {
                acc = __builtin_amdgcn_mfma_f32_16x16x32_bf16(a, blo, acc, 0, 0, 0);
            } else {
                short8 bhi = loadpack(xhi + d0);
                short8 z;
                #pragma unroll
                for (int q = 0; q < 8; q++) z[q] = 0;
                short8 alo = (m15 < fb) ? a : z;
                short8 ahi = (m15 < fb) ? z : a;
                acc = __builtin_amdgcn_mfma_f32_16x16x32_bf16(alo, blo, acc, 0, 0, 0);
                acc = __builtin_amdgcn_mfma_f32_16x16x32_bf16(ahi, bhi, acc, 0, 0, 0);
            }
        }
    }
    #pragma unroll
    for (int rg = 0; rg < 4; rg++) {
        const int f = f0 + koct * 4 + rg;
        float bias = 0.f;
        #pragma unroll
        for (int i = 0; i < 6; i++) {
            int j, pos;
            jpos(i, f, j, pos);
            bias += bp[i][pos];
        }
        out[((size_t)b * FDIM + f) * 64 + c0 + m15] = acc[rg] + bias;
    }
}

extern "C" void kernel_launch(void* const* d_in, const int* in_sizes, int n_in,
                              void* d_out, int out_size, void* d_ws, size_t ws_size,
                              hipStream_t stream) {
    (void)in_sizes; (void)n_in; (void)out_size;

    const float* x  = (const float*)d_in[0];
    const float* W0 = (const float*)d_in[1];
    const float* b0 = (const float*)d_in[2];
    const float* W1 = (const float*)d_in[3];
    const float* b1 = (const float*)d_in[4];
    const float* W2 = (const float*)d_in[5];
    const float* b2 = (const float*)d_in[6];
    const float* W3 = (const float*)d_in[7];
    const float* b3 = (const float*)d_in[8];
    const float* W4 = (const float*)d_in[9];
    const float* b4 = (const float*)d_in[10];
    const float* W5 = (const float*)d_in[11];
    const float* b5 = (const float*)d_in[12];
    float* out = (float*)d_out;

    if (ws_size >= TAB_BYTES) {
        char* ws = (char*)d_ws;
        olrs_prepinit<<<dim3((unsigned)(OUTELEMS / 4 / 256)), dim3(256), 0, stream>>>(
            W0, W1, W2, W3, W4, W5, b0, b1, b2, b3, b4, b5, ws, out);
        olrs_main15<<<dim3(2816), dim3(256), 0, stream>>>(x, ws, out);
    } else {
        olrs_fb<<<dim3(45 * 256), dim3(256), 0, stream>>>(
            x, W0, b0, W1, b1, W2, b2, W3, b3, W4, b4, W5, b5, out);
    }
}

// Round 16
// 82.826 us; speedup vs baseline: 1.1161x; 1.1161x over previous
//
#include <hip/hip_runtime.h>
#include <stdint.h>

// ---------------------------------------------------------------------------
// OutputLayerReverseSegments, round 16: coalesced x staging for ALL tokens.
// out[b,f,c] = sum_i x[b,c,t_i(f),:] . W_i[p_i(f),:] + sum_i b_i[p_i(f)]
// B=64, C=64, T=63, D=256, F=720, partitions k = {1,2,4,8,16,32}
//
// Diagnosis: tok>=7 per-wave x loads are 16B-per-lane at 64KB stride ->
// half of every 64B line wasted (2x x line traffic; ~138MB FETCH = re-hit
// halves) and 32 requests/instr jam the request path for all waves (why
// occupancy didn't help). Fix: tok7-62 block = (token, one b); block stages
// x[b][0:64][tok][:] fp32->bf16 into 2 LDS slabs with 128B-contiguous
// coalesced runs, ONE barrier (no atomics yet), then wave w computes item
// c0=(w>>1)*32 taking subtiles of parity w&1. W table 2-deep prefetch
// (stride 2), unsafeAtomicAdd, setprio. tok0-6 LDS-shared-x path verbatim
// from r14. Fused prepinit writes out = bias(f).
// Blocks: 768 (tok0-6) + 56*64 (tok7-62) = 4352.
// ---------------------------------------------------------------------------

#define FDIM 720
#define DDIM 256
#define TDIM 63
#define NSUBTOT 299                              // sum over (i,j) of ceil(len/16)
#define TAB_BYTES ((size_t)NSUBTOT * 8 * 1024)   // 2,449,408
#define OUTELEMS ((size_t)64 * FDIM * 64)        // 2,949,120
#define NPREPTHR (NSUBTOT * 8 * 64)              // 153,088

typedef __attribute__((ext_vector_type(8))) short short8;
typedef __attribute__((ext_vector_type(4))) float f32x4;

// pack 2 f32 -> 2 bf16 (round-half-up) in one u32: 2 adds + 1 v_perm
__device__ __forceinline__ uint32_t pkru(float a, float b) {
    uint32_t ua = __builtin_bit_cast(uint32_t, a) + 0x8000u;
    uint32_t ub = __builtin_bit_cast(uint32_t, b) + 0x8000u;
    return __builtin_amdgcn_perm(ub, ua, 0x07060302u);
}
__device__ __forceinline__ short8 loadpack(const float* p) {
    float4 v0 = *(const float4*)p;
    float4 v1 = *(const float4*)(p + 4);
    uint4 u;
    u.x = pkru(v0.x, v0.y);
    u.y = pkru(v0.z, v0.w);
    u.z = pkru(v1.x, v1.y);
    u.w = pkru(v1.z, v1.w);
    return __builtin_bit_cast(short8, u);
}

// HW float atomic add (avoid CAS-loop lowering)
__device__ __forceinline__ void atomAddF(float* p, float v) {
    unsafeAtomicAdd(p, v);
}

// partition index / position within part, for partition i at forecast f
__device__ __forceinline__ void jpos(int i, int f, int& j, int& pos) {
    switch (i) {
        case 0: j = 0;       pos = f;            break;
        case 1: j = f / 360; pos = f - 360 * j;  break;
        case 2: j = f / 180; pos = f - 180 * j;  break;
        case 3: j = f / 90;  pos = f - 90 * j;   break;
        case 4: j = f / 45;  pos = f - 45 * j;   break;
        default:
            if (f < 368) { j = f / 23;  pos = f - 23 * j; }
            else { int g = f - 368; int q = g / 22; j = 16 + q; pos = g - 22 * q; }
            break;
    }
}

// per-token parameters
__device__ __forceinline__ void tok_params(int tok, int& len, int& ns,
                                           int& start, int& tabsub) {
    if (tok < 1)       { len = 720; ns = 45; start = 0;
                         tabsub = 0; }
    else if (tok < 3)  { int j = tok - 1;  len = 360; ns = 23; start = 360 * j;
                         tabsub = 45 + j * 23; }
    else if (tok < 7)  { int j = tok - 3;  len = 180; ns = 12; start = 180 * j;
                         tabsub = 91 + j * 12; }
    else if (tok < 15) { int j = tok - 7;  len = 90;  ns = 6;  start = 90 * j;
                         tabsub = 139 + j * 6; }
    else if (tok < 31) { int j = tok - 15; len = 45;  ns = 3;  start = 45 * j;
                         tabsub = 187 + j * 3; }
    else               { int j = tok - 31;
                         len = (j < 16) ? 23 : 22;
                         start = (j < 16) ? 23 * j : 368 + 22 * (j - 16);
                         ns = 2; tabsub = 235 + j * 2; }
}

// ---------------------------------------------------------------------------
// Fused prep + init (unchanged from r11/r14).
// ---------------------------------------------------------------------------
__global__ __launch_bounds__(256) void olrs_prepinit(
    const float* __restrict__ W0, const float* __restrict__ W1,
    const float* __restrict__ W2, const float* __restrict__ W3,
    const float* __restrict__ W4, const float* __restrict__ W5,
    const float* __restrict__ b0, const float* __restrict__ b1,
    const float* __restrict__ b2, const float* __restrict__ b3,
    const float* __restrict__ b4, const float* __restrict__ b5,
    char* __restrict__ ws, float* __restrict__ out)
{
    const int gid = blockIdx.x * 256 + threadIdx.x;

    const size_t base = (size_t)gid * 4;
    if (base < OUTELEMS) {
        const int f = (int)((base >> 6) % FDIM);
        int j, p;
        float s = b0[f];
        jpos(1, f, j, p); s += b1[p];
        jpos(2, f, j, p); s += b2[p];
        jpos(3, f, j, p); s += b3[p];
        jpos(4, f, j, p); s += b4[p];
        jpos(5, f, j, p); s += b5[p];
        float4 o = {s, s, s, s};
        *(float4*)(out + base) = o;
    }

    if (gid < NPREPTHR) {
        const int lane = gid & 63;
        const int fid  = gid >> 6;
        const int ks = fid & 7;
        const int g  = fid >> 3;      // global subtile 0..298

        int len; const float* W; int s;
        if (g < 45)       { W = W0; len = 720; s = g; }
        else if (g < 91)  { int g2 = g - 45;  W = W1; len = 360; s = g2 % 23; }
        else if (g < 139) { int g2 = g - 91;  W = W2; len = 180; s = g2 % 12; }
        else if (g < 187) { int g2 = g - 139; W = W3; len = 90;  s = g2 % 6; }
        else if (g < 235) { int g2 = g - 187; W = W4; len = 45;  s = g2 % 3; }
        else              { int g2 = g - 235; W = W5; int j = g2 >> 1;
                            len = (j < 16) ? 23 : 22; s = g2 & 1; }

        const int m15  = lane & 15;
        const int koct = lane >> 4;
        const int pos  = s * 16 + m15;
        uint4 u = {0u, 0u, 0u, 0u};
        if (pos < len) {
            const float* src = W + (size_t)pos * DDIM + ks * 32 + koct * 8;
            float4 v0 = *(const float4*)src;
            float4 v1 = *(const float4*)(src + 4);
            u.x = pkru(v0.x, v0.y);
            u.y = pkru(v0.z, v0.w);
            u.z = pkru(v1.x, v1.y);
            u.w = pkru(v1.z, v1.w);
        }
        *(uint4*)(ws + (size_t)fid * 1024 + lane * 16) = u;
    }
}

// ---------------------------------------------------------------------------
// Main:
//  blocks [0,768)      : rid 0..5, tok0-6 LDS-shared-x roles (r14 verbatim).
//  blocks [768,4352)   : tok7-62, block = (token, one b): coalesced x slab
//                        staging (64c x 256d -> 2 LDS slabs), wave w ->
//                        item c0=(w>>1)*32, subtile parity w&1.
// Slab layout (16 KB, 32 c rows): addr ((ks*2+h)*64 + lane)*16 holds
//   x[c_base + h*16 + (lane&15)][ks*32 + (lane>>4)*8 ..+8) as bf16.
// ---------------------------------------------------------------------------
__global__ __launch_bounds__(256) void olrs_main16(
    const float* __restrict__ x,
    const char* __restrict__ ws,
    float* __restrict__ out)
{
    __shared__ char lds[32768];

    const int bid   = blockIdx.x;
    const int w     = threadIdx.x >> 6;
    const int lane  = threadIdx.x & 63;
    const int m15   = lane & 15;
    const int koct  = lane >> 4;

    if (bid < 768) {
        // ============== tok0-6: LDS-shared x slabs (r14 verbatim) ==========
        const int rid   = bid >> 7;      // 0..5
        const int ntile = bid & 127;
        const int b     = ntile >> 1;
        const int c0    = (ntile & 1) << 5;

        int tok, s0, slab;
        if (rid < 2)      { tok = 0;             s0 = rid * 24 + w * 6; slab = 0; }
        else if (rid < 4) { tok = rid - 1;       s0 = w * 6;            slab = 0; }
        else              { int tb = 3 + (rid - 4) * 2;
                            tok = tb + (w >> 1); s0 = (w & 1) * 6;      slab = w >> 1; }

        int len, ns, start, tabsub;
        tok_params(tok, len, ns, start, tabsub);
        const int send = (s0 + 6 < ns) ? (s0 + 6) : ns;

        const int nslab   = (rid >= 4) ? 2 : 1;
        const int tokbase = (rid < 2) ? 0 : ((rid < 4) ? (rid - 1) : 3 + (rid - 4) * 2);
        const int cc = threadIdx.x >> 3;   // 0..31
        const int t8 = threadIdx.x & 7;    // 0..7
        for (int sl = 0; sl < nslab; sl++) {
            const float* src = x + (((size_t)(b * 64 + c0 + cc)) * TDIM + tokbase + sl) * DDIM;
            char* dst = lds + sl * 16384;
            #pragma unroll
            for (int rep = 0; rep < 4; rep++) {
                const int d8 = t8 + rep * 8;            // 0..31
                float4 v0 = *(const float4*)(src + d8 * 8);
                float4 v1 = *(const float4*)(src + d8 * 8 + 4);
                uint4 u;
                u.x = pkru(v0.x, v0.y);
                u.y = pkru(v0.z, v0.w);
                u.z = pkru(v1.x, v1.y);
                u.w = pkru(v1.z, v1.w);
                const int slot = ((d8 >> 2) * 2 + (cc >> 4)) * 64
                               + (d8 & 3) * 16 + (cc & 15);
                *(uint4*)(dst + slot * 16) = u;
            }
        }
        __syncthreads();
        short8 xl[8], xh[8];
        const char* sb = lds + slab * 16384;
        #pragma unroll
        for (int ks = 0; ks < 8; ks++) {
            xl[ks] = *(const short8*)(sb + ((ks * 2 + 0) * 64 + lane) * 16);
            xh[ks] = *(const short8*)(sb + ((ks * 2 + 1) * 64 + lane) * 16);
        }

        const char* tab = ws + (size_t)tabsub * 8192 + lane * 16;
        float* obl = out + ((size_t)b * FDIM + start) * 64 + c0 + m15;
        float* obh = obl + 16;

        short8 wA[8], wB[8];
        auto loadW = [&](short8* wreg, int s) {
            const char* t = tab + (size_t)s * 8192;
            #pragma unroll
            for (int ks = 0; ks < 8; ks++)
                wreg[ks] = *(const short8*)(t + ks * 1024);
        };
        auto compute = [&](const short8* wreg, int s) {
            f32x4 al0 = {0.f, 0.f, 0.f, 0.f}, al1 = {0.f, 0.f, 0.f, 0.f};
            f32x4 ah0 = {0.f, 0.f, 0.f, 0.f}, ah1 = {0.f, 0.f, 0.f, 0.f};
            __builtin_amdgcn_s_setprio(1);
            #pragma unroll
            for (int ks = 0; ks < 8; ks += 2) {
                al0 = __builtin_amdgcn_mfma_f32_16x16x32_bf16(wreg[ks],     xl[ks],     al0, 0, 0, 0);
                ah0 = __builtin_amdgcn_mfma_f32_16x16x32_bf16(wreg[ks],     xh[ks],     ah0, 0, 0, 0);
                al1 = __builtin_amdgcn_mfma_f32_16x16x32_bf16(wreg[ks + 1], xl[ks + 1], al1, 0, 0, 0);
                ah1 = __builtin_amdgcn_mfma_f32_16x16x32_bf16(wreg[ks + 1], xh[ks + 1], ah1, 0, 0, 0);
            }
            __builtin_amdgcn_s_setprio(0);
            const int fl0 = s * 16 + koct * 4;
            #pragma unroll
            for (int rg = 0; rg < 4; rg++) {
                const int fl = fl0 + rg;
                if (fl < len) {
                    atomAddF(obl + (size_t)fl * 64, al0[rg] + al1[rg]);
                    atomAddF(obh + (size_t)fl * 64, ah0[rg] + ah1[rg]);
                }
            }
        };

        int s = s0;
        loadW(wA, s);
        for (;;) {
            if (s + 1 < send) loadW(wB, s + 1);
            compute(wA, s);
            if (++s >= send) break;
            if (s + 1 < send) loadW(wA, s + 1);
            compute(wB, s);
            if (++s >= send) break;
        }
    } else {
        // ========== tok7-62: coalesced full-b x staging, parity split ======
        const int idx = bid - 768;           // 0..3583
        const int tok = 7 + (idx >> 6);      // 7..62
        const int b   = idx & 63;

        int len, ns, start, tabsub;
        tok_params(tok, len, ns, start, tabsub);

        // ---- stage x[b][0:64][tok][:] -> 2 slabs, coalesced 128B runs
        {
            const int cc = threadIdx.x >> 2;   // 0..63 (c row)
            const int t4 = threadIdx.x & 3;    // 0..3
            const float* src = x + (((size_t)(b * 64 + cc)) * TDIM + tok) * DDIM;
            char* dst = lds + (cc >> 5) * 16384;
            const int h    = (cc >> 4) & 1;
            const int m15s = cc & 15;
            #pragma unroll
            for (int rep = 0; rep < 8; rep++) {
                const int d8 = rep * 4 + t4;            // 0..31
                float4 v0 = *(const float4*)(src + d8 * 8);
                float4 v1 = *(const float4*)(src + d8 * 8 + 4);
                uint4 u;
                u.x = pkru(v0.x, v0.y);
                u.y = pkru(v0.z, v0.w);
                u.z = pkru(v1.x, v1.y);
                u.w = pkru(v1.z, v1.w);
                const int slot = ((d8 >> 2) * 2 + h) * 64 + (d8 & 3) * 16 + m15s;
                *(uint4*)(dst + slot * 16) = u;
            }
        }
        __syncthreads();   // no atomics outstanding -> cheap drain

        const int item = w >> 1;             // 0,1 -> c0 = 0,32
        const int par  = w & 1;              // subtile parity
        const int c0   = item << 5;

        short8 xl[8], xh[8];
        const char* sb = lds + item * 16384;
        #pragma unroll
        for (int ks = 0; ks < 8; ks++) {
            xl[ks] = *(const short8*)(sb + ((ks * 2 + 0) * 64 + lane) * 16);
            xh[ks] = *(const short8*)(sb + ((ks * 2 + 1) * 64 + lane) * 16);
        }

        const char* tab = ws + (size_t)tabsub * 8192 + lane * 16;
        float* obl = out + ((size_t)b * FDIM + start) * 64 + c0 + m15;
        float* obh = obl + 16;

        short8 wA[8], wB[8];
        auto loadW = [&](short8* wreg, int s) {
            const char* t = tab + (size_t)s * 8192;
            #pragma unroll
            for (int ks = 0; ks < 8; ks++)
                wreg[ks] = *(const short8*)(t + ks * 1024);
        };
        auto compute = [&](const short8* wreg, int s) {
            f32x4 al0 = {0.f, 0.f, 0.f, 0.f}, al1 = {0.f, 0.f, 0.f, 0.f};
            f32x4 ah0 = {0.f, 0.f, 0.f, 0.f}, ah1 = {0.f, 0.f, 0.f, 0.f};
            __builtin_amdgcn_s_setprio(1);
            #pragma unroll
            for (int ks = 0; ks < 8; ks += 2) {
                al0 = __builtin_amdgcn_mfma_f32_16x16x32_bf16(wreg[ks],     xl[ks],     al0, 0, 0, 0);
                ah0 = __builtin_amdgcn_mfma_f32_16x16x32_bf16(wreg[ks],     xh[ks],     ah0, 0, 0, 0);
                al1 = __builtin_amdgcn_mfma_f32_16x16x32_bf16(wreg[ks + 1], xl[ks + 1], al1, 0, 0, 0);
                ah1 = __builtin_amdgcn_mfma_f32_16x16x32_bf16(wreg[ks + 1], xh[ks + 1], ah1, 0, 0, 0);
            }
            __builtin_amdgcn_s_setprio(0);
            const int fl0 = s * 16 + koct * 4;
            #pragma unroll
            for (int rg = 0; rg < 4; rg++) {
                const int fl = fl0 + rg;
                if (fl < len) {
                    atomAddF(obl + (size_t)fl * 64, al0[rg] + al1[rg]);
                    atomAddF(obh + (size_t)fl * 64, ah0[rg] + ah1[rg]);
                }
            }
        };

        // parity-strided 2-deep sweep (ns >= 2, par < ns always)
        int s = par;
        loadW(wA, s);
        for (;;) {
            if (s + 2 < ns) loadW(wB, s + 2);
            compute(wA, s);
            s += 2;
            if (s >= ns) break;
            if (s + 2 < ns) loadW(wA, s + 2);
            compute(wB, s);
            s += 2;
            if (s >= ns) break;
        }
    }
}

// ---------------------------------------------------------------------------
// Fallback (tiny ws): wave-independent direct-load kernel (round 3).
// ---------------------------------------------------------------------------
__device__ __forceinline__ int startf(int i, int j) {
    switch (i) {
        case 0: return 0;
        case 1: return 360 * j;
        case 2: return 180 * j;
        case 3: return 90 * j;
        case 4: return 45 * j;
        default: return (j < 16) ? 23 * j : 368 + 22 * (j - 16);
    }
}

__global__ __launch_bounds__(256) void olrs_fb(
    const float* __restrict__ x,
    const float* __restrict__ W0, const float* __restrict__ b0,
    const float* __restrict__ W1, const float* __restrict__ b1,
    const float* __restrict__ W2, const float* __restrict__ b2,
    const float* __restrict__ W3, const float* __restrict__ b3,
    const float* __restrict__ W4, const float* __restrict__ b4,
    const float* __restrict__ W5, const float* __restrict__ b5,
    float* __restrict__ out)
{
    const float* Wp[6] = {W0, W1, W2, W3, W4, W5};
    const float* bp[6] = {b0, b1, b2, b3, b4, b5};
    const int TB[6] = {0, 1, 3, 7, 15, 31};

    const int wid  = blockIdx.x * 4 + (threadIdx.x >> 6);
    const int lane = threadIdx.x & 63;
    const int ft   = wid % 45;
    const int bc   = wid / 45;
    const int b    = bc >> 2;
    const int c0   = (bc & 3) << 4;
    const int f0   = ft << 4;
    const int m15  = lane & 15;
    const int koct = lane >> 4;
    const size_t xrow = (size_t)(b * 64 + c0 + m15) * TDIM;

    f32x4 acc = {0.f, 0.f, 0.f, 0.f};
    #pragma unroll
    for (int i = 0; i < 6; i++) {
        int jlo, plo, jhi, phi;
        jpos(i, f0, jlo, plo);
        jpos(i, f0 + 15, jhi, phi);
        const bool cross = (jhi > jlo);
        const int fb = cross ? (startf(i, jhi) - f0) : 16;
        const float* xlo = x + (xrow + TB[i] + jlo) * DDIM;
        const float* xhi = x + (xrow + TB[i] + jhi) * DDIM;
        int jw, pw;
        jpos(i, f0 + m15, jw, pw);
        const float* wsrc = Wp[i] + (size_t)pw * DDIM;
        #pragma unroll
        for (int ks = 0; ks < 8; ks++) {
            const int d0 = ks * 32 + koct * 8;
            short8 a = loadpack(wsrc + d0);
            short8 blo = loadpack(xlo + d0);
            if (!cross) {
                acc = __builtin_amdgcn_mfma_f32_16x16x32_bf16(a, blo, acc, 0, 0, 0);
            } else {
                short8 bhi = loadpack(xhi + d0);
                short8 z;
                #pragma unroll
                for (int q = 0; q < 8; q++) z[q] = 0;
                short8 alo = (m15 < fb) ? a : z;
                short8 ahi = (m15 < fb) ? z : a;
                acc = __builtin_amdgcn_mfma_f32_16x16x32_bf16(alo, blo, acc, 0, 0, 0);
                acc = __builtin_amdgcn_mfma_f32_16x16x32_bf16(ahi, bhi, acc, 0, 0, 0);
            }
        }
    }
    #pragma unroll
    for (int rg = 0; rg < 4; rg++) {
        const int f = f0 + koct * 4 + rg;
        float bias = 0.f;
        #pragma unroll
        for (int i = 0; i < 6; i++) {
            int j, pos;
            jpos(i, f, j, pos);
            bias += bp[i][pos];
        }
        out[((size_t)b * FDIM + f) * 64 + c0 + m15] = acc[rg] + bias;
    }
}

extern "C" void kernel_launch(void* const* d_in, const int* in_sizes, int n_in,
                              void* d_out, int out_size, void* d_ws, size_t ws_size,
                              hipStream_t stream) {
    (void)in_sizes; (void)n_in; (void)out_size;

    const float* x  = (const float*)d_in[0];
    const float* W0 = (const float*)d_in[1];
    const float* b0 = (const float*)d_in[2];
    const float* W1 = (const float*)d_in[3];
    const float* b1 = (const float*)d_in[4];
    const float* W2 = (const float*)d_in[5];
    const float* b2 = (const float*)d_in[6];
    const float* W3 = (const float*)d_in[7];
    const float* b3 = (const float*)d_in[8];
    const float* W4 = (const float*)d_in[9];
    const float* b4 = (const float*)d_in[10];
    const float* W5 = (const float*)d_in[11];
    const float* b5 = (const float*)d_in[12];
    float* out = (float*)d_out;

    if (ws_size >= TAB_BYTES) {
        char* ws = (char*)d_ws;
        olrs_prepinit<<<dim3((unsigned)(OUTELEMS / 4 / 256)), dim3(256), 0, stream>>>(
            W0, W1, W2, W3, W4, W5, b0, b1, b2, b3, b4, b5, ws, out);
        olrs_main16<<<dim3(4352), dim3(256), 0, stream>>>(x, ws, out);
    } else {
        olrs_fb<<<dim3(45 * 256), dim3(256), 0, stream>>>(
            x, W0, b0, W1, b1, W2, b2, W3, b3, W4, b4, W5, b5, out);
    }
}